// Round 7
// baseline (655.050 us; speedup 1.0000x reference)
//
#include <hip/hip_runtime.h>
#include <hip/hip_bf16.h>
#include <float.h>

#define K_NEI 9
#define M 4096
#define N 65536
#define D 128
#define SEGS 32
#define SEG_LEN (N / SEGS)     // 2048 bank rows per segment
#define QB 128                 // queries per block
#define BB 64                  // bank rows per chunk
#define CHUNKS (SEG_LEN / BB)  // 32
#define QGROUPS (M / QB)       // 32

typedef __bf16 bf16x8 __attribute__((ext_vector_type(8)));
typedef float floatx4 __attribute__((ext_vector_type(4)));

static __device__ inline floatx4 mfma16(bf16x8 a, bf16x8 b, floatx4 c) {
    return __builtin_amdgcn_mfma_f32_16x16x32_bf16(a, b, c, 0, 0, 0);
}

// async global->LDS, 16B per lane, dest = lds_base + lane*16
#define GL_LDS16(gp, lp)                                                     \
    __builtin_amdgcn_global_load_lds(                                        \
        (const __attribute__((address_space(1))) unsigned int*)(const void*)(gp), \
        (__attribute__((address_space(3))) unsigned int*)(void*)(lp), 16, 0, 0)

// ---- sorted-9 toolkit -----------------------------------------------------
static __device__ inline void ce(float& a, float& b) {
    float lo = fminf(a, b), hi = fmaxf(a, b); a = lo; b = hi;
}
// canonical optimal 25-CE / depth-7 sorting network for 9 (ascending)
static __device__ inline void sort9(float t[K_NEI]) {
    ce(t[0],t[3]); ce(t[1],t[7]); ce(t[2],t[5]); ce(t[4],t[8]);
    ce(t[0],t[7]); ce(t[2],t[4]); ce(t[3],t[8]); ce(t[5],t[6]);
    ce(t[0],t[2]); ce(t[1],t[3]); ce(t[4],t[5]); ce(t[7],t[8]);
    ce(t[1],t[4]); ce(t[3],t[6]); ce(t[5],t[7]);
    ce(t[0],t[1]); ce(t[2],t[4]); ce(t[3],t[5]); ce(t[6],t[8]);
    ce(t[2],t[3]); ce(t[4],t[5]); ce(t[6],t[7]);
    ce(t[1],t[2]); ce(t[3],t[4]); ce(t[5],t[6]);
}
// t, o sorted ascending -> t = sorted 9 smallest of union (bitonic min trick)
static __device__ inline void merge9(float t[K_NEI], const float o[K_NEI]) {
    float m[K_NEI];
#pragma unroll
    for (int i = 0; i < K_NEI; ++i) m[i] = fminf(t[i], o[K_NEI - 1 - i]);
    sort9(m);
#pragma unroll
    for (int i = 0; i < K_NEI; ++i) t[i] = m[i];
}
// pool the 4 partner lanes (lane ^16, ^32): all 4 end with identical exact
// top-9 of the quad's union. ONLY valid if the 4 lists are element-disjoint.
static __device__ inline void quad_merge(float t[K_NEI]) {
    float o[K_NEI];
#pragma unroll
    for (int i = 0; i < K_NEI; ++i) o[i] = __shfl_xor(t[i], 16, 64);
    merge9(t, o);
#pragma unroll
    for (int i = 0; i < K_NEI; ++i) o[i] = __shfl_xor(t[i], 32, 64);
    merge9(t, o);
}

// ---------------------------------------------------------------------------
// Kernel 1 (fused prep): fp32 -> bf16 convert + row norms for BOTH inputs,
// plus per-call init of thr_g (gates) and done (qgroup counters) -- ws is
// re-poisoned 0xAA before every timed call.
// ---------------------------------------------------------------------------
__global__ void prep_kernel(const float* __restrict__ bank,
                            const float* __restrict__ feats,
                            __hip_bfloat16* __restrict__ bankbf,
                            __hip_bfloat16* __restrict__ featbf,
                            float* __restrict__ bsqn,
                            float* __restrict__ qsq,
                            int* __restrict__ thr_g,
                            int* __restrict__ done) {
    int row  = (int)((blockIdx.x * blockDim.x + threadIdx.x) >> 6);
    int lane = threadIdx.x & 63;
    if (row >= N + M) return;
    const float* src = (row < N) ? (bank + (size_t)row * D)
                                 : (feats + (size_t)(row - N) * D);
    __hip_bfloat16* dst = (row < N) ? (bankbf + (size_t)row * D)
                                    : (featbf + (size_t)(row - N) * D);
    float2 v = ((const float2*)src)[lane];
    float s = v.x * v.x + v.y * v.y;
    dst[lane * 2 + 0] = __float2bfloat16(v.x);
    dst[lane * 2 + 1] = __float2bfloat16(v.y);
#pragma unroll
    for (int off = 32; off > 0; off >>= 1) s += __shfl_down(s, off, 64);
    if (lane == 0) {
        if (row < N) {
            bsqn[row] = -0.5f * s;
        } else {
            qsq[row - N] = s;
            thr_g[row - N] = 0x7f7f7f7f;   // 3.39e38f
        }
    }
    if (lane == 1 && row >= N && row < N + QGROUPS) done[row - N] = 0;
}

// ---------------------------------------------------------------------------
// Kernel 2: MFMA distance GEMM + fused per-query top-9 + fused final merge.
// grid = 1024 blocks (4/CU co-resident -- round-6 lesson: 2 blocks/CU left
// >50% of cycles stalled) of 256 threads (4 waves); 32 KB LDS double buffer.
// XCD-swizzled: seg%8 == blockIdx%8 for bank-segment L2 locality.
//
// acc init = -0.5*bs (fp32) => acc = dot - 0.5*bs => d2 = qs - 2*acc.
// bsqn + thr_g for chunk ch+1 are PREFETCHED INTO REGISTERS alongside the
// LDS staging (round-6 lesson: same-chunk consumption forced a mid-body
// vmcnt drain); consumed one iteration later when guaranteed landed.
// Gate: d2 <= g  <=>  acc >= h = 0.5*(qs - g): 1 reg-max + 1 v_cmp per 4
// elements. Gate-merge events (ch = 0,1,2,3,7,15,23): each 4-lane quad
// computes its EXACT pooled top-9 (disjoint lists: leader keeps, followers
// clear -- round-5 bug) and publishes the pooled 9th (atomicMin, dirty-skip).
// Last seg-block per qgroup (done-counter + threadfence + agent-scope loads)
// folds the 32 sorted per-seg lists and writes the output.
// ---------------------------------------------------------------------------
__global__ __launch_bounds__(256, 4)
void knn_main(const __hip_bfloat16* __restrict__ bankbf,
              const __hip_bfloat16* __restrict__ featbf,
              const float* __restrict__ bsqn,
              const float* __restrict__ qsqp,
              int* __restrict__ thr_g,
              float* __restrict__ part,
              int* __restrict__ done,
              float* __restrict__ out) {
    __shared__ __align__(16) union SMEM {
        short bt[2][16 * 512];       // 2 x 16 KB bank tile (double buffer)
        float pool[QB][K_NEI];       // 4.6 KB epilogue cross-wave pool
    } sm;
    __shared__ int sm_last;

    const int tid  = threadIdx.x;
    const int lane = tid & 63;
    const int wv   = tid >> 6;
    const int qw   = wv & 1;        // query half of block (64 queries)
    const int bw   = wv >> 1;       // bank half of chunk (32 rows)
    // XCD swizzle: seg%8 == blockIdx%8
    const int s8  = blockIdx.x & 7;
    const int t_  = blockIdx.x >> 3;
    const int bq  = t_ & 31;
    const int seg = ((t_ >> 5) << 3) | s8;
    const int qbase  = bq * QB;
    const int cbase0 = seg * SEG_LEN;
    const int l15 = lane & 15, l4 = lane >> 4;

    // query fragments (B operand), cached in registers for the whole block
    bf16x8 qf[4][4];
    float qs4[4];
    int qglob[4], qloc[4];
#pragma unroll
    for (int qt = 0; qt < 4; ++qt) {
        int q = qbase + qw * 64 + qt * 16 + l15;
        qglob[qt] = q;
        qloc[qt]  = qw * 64 + qt * 16 + l15;
        qs4[qt]   = qsqp[q];
#pragma unroll
        for (int ks = 0; ks < 4; ++ks)
            qf[qt][ks] = *(const bf16x8*)(featbf + (size_t)q * D + ks * 32 + l4 * 8);
    }

    float t9[4][K_NEI];
    float g[4], lastpub[4];
#pragma unroll
    for (int qt = 0; qt < 4; ++qt) {
        g[qt] = FLT_MAX;
        lastpub[qt] = FLT_MAX;
#pragma unroll
        for (int j = 0; j < K_NEI; ++j) t9[qt][j] = FLT_MAX;
    }

    // prologue: stage chunk 0 into buffer 0 (16 regions, 4 per wave)
#pragma unroll
    for (int i = 0; i < 4; ++i) {
        int rgn = wv * 4 + i;
        int bt = rgn >> 2, ks = rgn & 3;
        const __hip_bfloat16* gp =
            bankbf + (size_t)(cbase0 + bt * 16 + l15) * D + ks * 32 + l4 * 8;
        GL_LDS16(gp, &sm.bt[0][rgn * 512]);
    }
    // prologue register prefetch for chunk 0
    floatx4 nsq_p[2];
    int tg_p[4];
#pragma unroll
    for (int bb = 0; bb < 2; ++bb)
        nsq_p[bb] = *(const floatx4*)&bsqn[cbase0 + (bw * 2 + bb) * 16 + l4 * 4];
#pragma unroll
    for (int qt = 0; qt < 4; ++qt)
        tg_p[qt] = __hip_atomic_load(&thr_g[qglob[qt]], __ATOMIC_RELAXED,
                                     __HIP_MEMORY_SCOPE_AGENT);

#pragma unroll 1
    for (int ch = 0; ch < CHUNKS; ++ch) {
        const int cur = ch & 1;
        __syncthreads();  // drains own vmcnt -> buf[cur] + prefetch regs ready

        // consume this chunk's prefetched values (already landed)
        floatx4 ini[2];
        int tg[4];
#pragma unroll
        for (int bb = 0; bb < 2; ++bb) ini[bb] = nsq_p[bb];
#pragma unroll
        for (int qt = 0; qt < 4; ++qt) tg[qt] = tg_p[qt];

        // issue next chunk's staging + register prefetches immediately
        if (ch + 1 < CHUNKS) {
            const int cb1 = cbase0 + (ch + 1) * BB;
#pragma unroll
            for (int i = 0; i < 4; ++i) {
                int rgn = wv * 4 + i;
                int bt = rgn >> 2, ks = rgn & 3;
                const __hip_bfloat16* gp =
                    bankbf + (size_t)(cb1 + bt * 16 + l15) * D + ks * 32 + l4 * 8;
                GL_LDS16(gp, &sm.bt[cur ^ 1][rgn * 512]);
            }
#pragma unroll
            for (int bb = 0; bb < 2; ++bb)
                nsq_p[bb] = *(const floatx4*)&bsqn[cb1 + (bw * 2 + bb) * 16 + l4 * 4];
#pragma unroll
            for (int qt = 0; qt < 4; ++qt)
                tg_p[qt] = __hip_atomic_load(&thr_g[qglob[qt]], __ATOMIC_RELAXED,
                                             __HIP_MEMORY_SCOPE_AGENT);
        }

        // acc init = -0.5*bs (D-layout row = l4*4+r)
        floatx4 acc[2][4];
#pragma unroll
        for (int bb = 0; bb < 2; ++bb)
#pragma unroll
            for (int qt = 0; qt < 4; ++qt) acc[bb][qt] = ini[bb];
        // MFMA: 2 bank-tiles x 4 query-tiles, K = 128 (4 ksteps of 32)
#pragma unroll
        for (int ks = 0; ks < 4; ++ks) {
            bf16x8 af[2];
#pragma unroll
            for (int bb = 0; bb < 2; ++bb)
                af[bb] = *(const bf16x8*)
                    &sm.bt[cur][((bw * 2 + bb) * 4 + ks) * 512 + lane * 8];
#pragma unroll
            for (int bb = 0; bb < 2; ++bb)
#pragma unroll
                for (int qt = 0; qt < 4; ++qt)
                    acc[bb][qt] = mfma16(af[bb], qf[qt][ks], acc[bb][qt]);
        }

        // gates -> thresholds on raw acc (loosening guards transform rounding)
        float h[4];
#pragma unroll
        for (int qt = 0; qt < 4; ++qt) {
            g[qt] = fminf(g[qt], __int_as_float(tg[qt]));
            h[qt] = 0.5f * (qs4[qt] - g[qt] * 1.0000005f);
        }

        // selection: 1 reg-max + 1 v_cmp per 4 elements; rare insert path
#pragma unroll
        for (int bb = 0; bb < 2; ++bb) {
#pragma unroll
            for (int qt = 0; qt < 4; ++qt) {
                float a0 = acc[bb][qt][0], a1 = acc[bb][qt][1];
                float a2 = acc[bb][qt][2], a3 = acc[bb][qt][3];
                float mx = fmaxf(fmaxf(a0, a1), fmaxf(a2, a3));
                if (__ballot(mx >= h[qt])) {
#pragma unroll
                    for (int r = 0; r < 4; ++r) {
                        float a = acc[bb][qt][r];
                        if (a >= h[qt]) {
                            float d2 = fmaxf(fmaf(-2.f, a, qs4[qt]), 0.f);
                            if (d2 <= g[qt]) {
                                t9[qt][K_NEI - 1] = d2;
#pragma unroll
                                for (int s = K_NEI - 1; s > 0; --s)
                                    ce(t9[qt][s - 1], t9[qt][s]);
                                g[qt] = fminf(g[qt], t9[qt][K_NEI - 1]);
                            }
                        }
                    }
                }
            }
        }
        // gate-merge events (ch = 0,1,2,3,7,15,23 -> mask 0x80808F):
        // exact quad pool -> publish 9th; leader keeps, followers clear.
        if ((0x80808Fu >> ch) & 1) {
#pragma unroll
            for (int qt = 0; qt < 4; ++qt) {
                quad_merge(t9[qt]);
                float nth = t9[qt][K_NEI - 1];
                g[qt] = fminf(g[qt], nth);
                if (l4 == 0) {
                    if (nth < lastpub[qt]) {
                        atomicMin(&thr_g[qglob[qt]], __float_as_int(nth));
                        lastpub[qt] = nth;
                    }
                } else {
                    // follower: reset so lists stay element-disjoint
#pragma unroll
                    for (int j = 0; j < K_NEI; ++j) t9[qt][j] = FLT_MAX;
                }
            }
        }
    }

    // ---- epilogue: pool quad (disjoint), then cross-wave (bw) via LDS -----
#pragma unroll
    for (int qt = 0; qt < 4; ++qt) quad_merge(t9[qt]);
    __syncthreads();            // last chunk's ds_reads done; bt area reusable
    if (bw == 0 && l4 == 0) {
#pragma unroll
        for (int qt = 0; qt < 4; ++qt)
#pragma unroll
            for (int j = 0; j < K_NEI; ++j)
                sm.pool[qloc[qt]][j] = t9[qt][j];
    }
    __syncthreads();
    if (bw == 1 && l4 == 0) {
#pragma unroll
        for (int qt = 0; qt < 4; ++qt) {
            float o[K_NEI];
#pragma unroll
            for (int j = 0; j < K_NEI; ++j) o[j] = sm.pool[qloc[qt]][j];
            merge9(t9[qt], o);   // block-pooled sorted top-9 for this segment
            float* dst = part + ((size_t)(qbase + qloc[qt]) * SEGS + seg) * K_NEI;
#pragma unroll
            for (int j = 0; j < K_NEI; ++j) dst[j] = t9[qt][j];
        }
    }

    // ---- fused final: last seg-block of this qgroup folds 32 sorted lists --
    __threadfence();            // release our part writes device-wide
    __syncthreads();
    if (tid == 0)
        sm_last = (atomicAdd(&done[bq], 1) == SEGS - 1) ? 1 : 0;
    __syncthreads();
    if (sm_last && tid < QB) {
        int q = qbase + tid;
        const float* p = part + (size_t)q * SEGS * K_NEI;
        float R[K_NEI], nx[K_NEI];
#pragma unroll
        for (int j = 0; j < K_NEI; ++j)
            R[j] = __hip_atomic_load(p + j, __ATOMIC_RELAXED,
                                     __HIP_MEMORY_SCOPE_AGENT);
#pragma unroll
        for (int j = 0; j < K_NEI; ++j)
            nx[j] = __hip_atomic_load(p + K_NEI + j, __ATOMIC_RELAXED,
                                      __HIP_MEMORY_SCOPE_AGENT);
#pragma unroll 1
        for (int s = 1; s < SEGS; ++s) {
            float o[K_NEI];
#pragma unroll
            for (int j = 0; j < K_NEI; ++j) o[j] = nx[j];
            if (s + 1 < SEGS) {
#pragma unroll
                for (int j = 0; j < K_NEI; ++j)
                    nx[j] = __hip_atomic_load(p + (s + 1) * K_NEI + j,
                                              __ATOMIC_RELAXED,
                                              __HIP_MEMORY_SCOPE_AGENT);
            }
            merge9(R, o);
        }
        float sum = 0.f;
#pragma unroll
        for (int j = 0; j < K_NEI; ++j) sum += sqrtf(fmaxf(R[j], 0.f));
        out[q] = sum * (1.0f / 9.0f);
    }
}

// ---------------------------------------------------------------------------
extern "C" void kernel_launch(void* const* d_in, const int* in_sizes, int n_in,
                              void* d_out, int out_size, void* d_ws, size_t ws_size,
                              hipStream_t stream) {
    const float* feats = (const float*)d_in[0];   // [M, D]
    const float* bank  = (const float*)d_in[1];   // [N, D]

    char* w = (char*)d_ws;
    __hip_bfloat16* bankbf = (__hip_bfloat16*)w;                       // 16 MB
    __hip_bfloat16* featbf = (__hip_bfloat16*)(w + (size_t)N * D * 2); // 1 MB
    float* bsqn = (float*)(w + (size_t)(N + M) * D * 2);               // 256 KB
    float* qsqp = bsqn + N;                                            // 16 KB
    float* part = qsqp + M;                                            // 4.5 MB
    int*   thr_g = (int*)(part + (size_t)M * SEGS * K_NEI);            // 16 KB
    int*   done  = thr_g + M;                                          // 128 B
    float* out  = (float*)d_out;

    prep_kernel<<<(N + M) / 4, 256, 0, stream>>>(bank, feats, bankbf, featbf,
                                                 bsqn, qsqp, thr_g, done);
    knn_main<<<QGROUPS * SEGS, 256, 0, stream>>>(bankbf, featbf, bsqn, qsqp,
                                                 thr_g, part, done, out);
}

// Round 8
// 537.518 us; speedup vs baseline: 1.2187x; 1.2187x over previous
//
#include <hip/hip_runtime.h>
#include <hip/hip_bf16.h>
#include <float.h>

#define K_NEI 9
#define M 4096
#define N 65536
#define D 128
#define SEGS 32
#define SEG_LEN (N / SEGS)     // 2048 bank rows per segment
#define QB 128                 // queries per block
#define BB 64                  // bank rows per chunk
#define CHUNKS (SEG_LEN / BB)  // 32
#define QGROUPS (M / QB)       // 32

typedef __bf16 bf16x8 __attribute__((ext_vector_type(8)));
typedef float floatx4 __attribute__((ext_vector_type(4)));

static __device__ inline floatx4 mfma16(bf16x8 a, bf16x8 b, floatx4 c) {
    return __builtin_amdgcn_mfma_f32_16x16x32_bf16(a, b, c, 0, 0, 0);
}

// async global->LDS, 16B per lane, dest = lds_base + lane*16
#define GL_LDS16(gp, lp)                                                     \
    __builtin_amdgcn_global_load_lds(                                        \
        (const __attribute__((address_space(1))) unsigned int*)(const void*)(gp), \
        (__attribute__((address_space(3))) unsigned int*)(void*)(lp), 16, 0, 0)

// ---- sorted-9 toolkit -----------------------------------------------------
static __device__ inline void ce(float& a, float& b) {
    float lo = fminf(a, b), hi = fmaxf(a, b); a = lo; b = hi;
}
// canonical optimal 25-CE / depth-7 sorting network for 9 (ascending)
static __device__ inline void sort9(float t[K_NEI]) {
    ce(t[0],t[3]); ce(t[1],t[7]); ce(t[2],t[5]); ce(t[4],t[8]);
    ce(t[0],t[7]); ce(t[2],t[4]); ce(t[3],t[8]); ce(t[5],t[6]);
    ce(t[0],t[2]); ce(t[1],t[3]); ce(t[4],t[5]); ce(t[7],t[8]);
    ce(t[1],t[4]); ce(t[3],t[6]); ce(t[5],t[7]);
    ce(t[0],t[1]); ce(t[2],t[4]); ce(t[3],t[5]); ce(t[6],t[8]);
    ce(t[2],t[3]); ce(t[4],t[5]); ce(t[6],t[7]);
    ce(t[1],t[2]); ce(t[3],t[4]); ce(t[5],t[6]);
}
// t, o sorted ascending -> t = sorted 9 smallest of union (bitonic min trick)
static __device__ inline void merge9(float t[K_NEI], const float o[K_NEI]) {
    float m[K_NEI];
#pragma unroll
    for (int i = 0; i < K_NEI; ++i) m[i] = fminf(t[i], o[K_NEI - 1 - i]);
    sort9(m);
#pragma unroll
    for (int i = 0; i < K_NEI; ++i) t[i] = m[i];
}
// pool the 4 partner lanes (lane ^16, ^32): all 4 end with identical exact
// top-9 of the quad's union. ONLY valid if the 4 lists are element-disjoint.
static __device__ inline void quad_merge(float t[K_NEI]) {
    float o[K_NEI];
#pragma unroll
    for (int i = 0; i < K_NEI; ++i) o[i] = __shfl_xor(t[i], 16, 64);
    merge9(t, o);
#pragma unroll
    for (int i = 0; i < K_NEI; ++i) o[i] = __shfl_xor(t[i], 32, 64);
    merge9(t, o);
}

// ---------------------------------------------------------------------------
// Kernel 1 (fused prep): fp32 -> bf16 convert + row norms for BOTH inputs,
// plus per-call init of thr_g (gates) and done (qgroup counters) -- ws is
// re-poisoned 0xAA before every timed call.
// ---------------------------------------------------------------------------
__global__ void prep_kernel(const float* __restrict__ bank,
                            const float* __restrict__ feats,
                            __hip_bfloat16* __restrict__ bankbf,
                            __hip_bfloat16* __restrict__ featbf,
                            float* __restrict__ bsqn,
                            float* __restrict__ qsq,
                            int* __restrict__ thr_g,
                            int* __restrict__ done) {
    int row  = (int)((blockIdx.x * blockDim.x + threadIdx.x) >> 6);
    int lane = threadIdx.x & 63;
    if (row >= N + M) return;
    const float* src = (row < N) ? (bank + (size_t)row * D)
                                 : (feats + (size_t)(row - N) * D);
    __hip_bfloat16* dst = (row < N) ? (bankbf + (size_t)row * D)
                                    : (featbf + (size_t)(row - N) * D);
    float2 v = ((const float2*)src)[lane];
    float s = v.x * v.x + v.y * v.y;
    dst[lane * 2 + 0] = __float2bfloat16(v.x);
    dst[lane * 2 + 1] = __float2bfloat16(v.y);
#pragma unroll
    for (int off = 32; off > 0; off >>= 1) s += __shfl_down(s, off, 64);
    if (lane == 0) {
        if (row < N) {
            bsqn[row] = -0.5f * s;
        } else {
            qsq[row - N] = s;
            thr_g[row - N] = 0x7f7f7f7f;   // 3.39e38f
        }
    }
    if (lane == 1 && row >= N && row < N + QGROUPS) done[row - N] = 0;
}

// ---------------------------------------------------------------------------
// Kernel 2: MFMA distance GEMM + fused per-query top-9 + fused final merge.
// grid = 1024 blocks of 256 threads (4 waves); 32 KB LDS double buffer.
// __launch_bounds__(256,3): ROUND-7 LESSON -- gfx950's UNIFIED VGPR/AGPR
// file means the 32 AGPR accumulators count against the per-wave budget.
// (256,4) capped arch VGPRs at 64 vs ~130 live -> scratch spill (FETCH
// 1 GB, WRITE 447 MB). (256,3) gives a 170-reg budget: ~162 demand fits,
// 3 blocks/CU = 12 waves/CU (1.5x round 6) with zero spill.
// XCD-swizzled: seg%8 == blockIdx%8 for bank-segment L2 locality.
//
// acc init = -0.5*bs (fp32) => acc = dot - 0.5*bs => d2 = qs - 2*acc.
// bsqn + thr_g for chunk ch+1 are prefetched into registers alongside the
// LDS staging (round-6 lesson: same-chunk consumption forced a mid-body
// vmcnt drain); consumed one iteration later when guaranteed landed.
// Gate: d2 <= g  <=>  acc >= h = 0.5*(qs - g): 1 reg-max + 1 v_cmp per 4
// elements. Gate-merge events (ch = 0,1,2,3,7,15,23): each 4-lane quad
// computes its EXACT pooled top-9 (disjoint lists: leader keeps, followers
// clear -- round-5 bug) and publishes the pooled 9th (atomicMin, dirty-skip).
// Last seg-block per qgroup (done-counter + threadfence + agent-scope loads)
// folds the 32 sorted per-seg lists and writes the output.
// ---------------------------------------------------------------------------
__global__ __launch_bounds__(256, 3)
void knn_main(const __hip_bfloat16* __restrict__ bankbf,
              const __hip_bfloat16* __restrict__ featbf,
              const float* __restrict__ bsqn,
              const float* __restrict__ qsqp,
              int* __restrict__ thr_g,
              float* __restrict__ part,
              int* __restrict__ done,
              float* __restrict__ out) {
    __shared__ __align__(16) union SMEM {
        short bt[2][16 * 512];       // 2 x 16 KB bank tile (double buffer)
        float pool[QB][K_NEI];       // 4.6 KB epilogue cross-wave pool
    } sm;
    __shared__ int sm_last;

    const int tid  = threadIdx.x;
    const int lane = tid & 63;
    const int wv   = tid >> 6;
    const int qw   = wv & 1;        // query half of block (64 queries)
    const int bw   = wv >> 1;       // bank half of chunk (32 rows)
    // XCD swizzle: seg%8 == blockIdx%8
    const int s8  = blockIdx.x & 7;
    const int t_  = blockIdx.x >> 3;
    const int bq  = t_ & 31;
    const int seg = ((t_ >> 5) << 3) | s8;
    const int qbase  = bq * QB;
    const int cbase0 = seg * SEG_LEN;
    const int l15 = lane & 15, l4 = lane >> 4;

    // query fragments (B operand), cached in registers for the whole block
    bf16x8 qf[4][4];
    float qs4[4];
    int qglob[4], qloc[4];
#pragma unroll
    for (int qt = 0; qt < 4; ++qt) {
        int q = qbase + qw * 64 + qt * 16 + l15;
        qglob[qt] = q;
        qloc[qt]  = qw * 64 + qt * 16 + l15;
        qs4[qt]   = qsqp[q];
#pragma unroll
        for (int ks = 0; ks < 4; ++ks)
            qf[qt][ks] = *(const bf16x8*)(featbf + (size_t)q * D + ks * 32 + l4 * 8);
    }

    float t9[4][K_NEI];
    float g[4], lastpub[4];
#pragma unroll
    for (int qt = 0; qt < 4; ++qt) {
        g[qt] = FLT_MAX;
        lastpub[qt] = FLT_MAX;
#pragma unroll
        for (int j = 0; j < K_NEI; ++j) t9[qt][j] = FLT_MAX;
    }

    // prologue: stage chunk 0 into buffer 0 (16 regions, 4 per wave)
#pragma unroll
    for (int i = 0; i < 4; ++i) {
        int rgn = wv * 4 + i;
        int bt = rgn >> 2, ks = rgn & 3;
        const __hip_bfloat16* gp =
            bankbf + (size_t)(cbase0 + bt * 16 + l15) * D + ks * 32 + l4 * 8;
        GL_LDS16(gp, &sm.bt[0][rgn * 512]);
    }
    // prologue register prefetch for chunk 0
    floatx4 nsq_p[2];
    int tg_p[4];
#pragma unroll
    for (int bb = 0; bb < 2; ++bb)
        nsq_p[bb] = *(const floatx4*)&bsqn[cbase0 + (bw * 2 + bb) * 16 + l4 * 4];
#pragma unroll
    for (int qt = 0; qt < 4; ++qt)
        tg_p[qt] = __hip_atomic_load(&thr_g[qglob[qt]], __ATOMIC_RELAXED,
                                     __HIP_MEMORY_SCOPE_AGENT);

#pragma unroll 1
    for (int ch = 0; ch < CHUNKS; ++ch) {
        const int cur = ch & 1;
        __syncthreads();  // drains own vmcnt -> buf[cur] + prefetch regs ready

        // consume this chunk's prefetched values (already landed)
        floatx4 ini[2];
        int tg[4];
#pragma unroll
        for (int bb = 0; bb < 2; ++bb) ini[bb] = nsq_p[bb];
#pragma unroll
        for (int qt = 0; qt < 4; ++qt) tg[qt] = tg_p[qt];

        // issue next chunk's staging + register prefetches immediately
        if (ch + 1 < CHUNKS) {
            const int cb1 = cbase0 + (ch + 1) * BB;
#pragma unroll
            for (int i = 0; i < 4; ++i) {
                int rgn = wv * 4 + i;
                int bt = rgn >> 2, ks = rgn & 3;
                const __hip_bfloat16* gp =
                    bankbf + (size_t)(cb1 + bt * 16 + l15) * D + ks * 32 + l4 * 8;
                GL_LDS16(gp, &sm.bt[cur ^ 1][rgn * 512]);
            }
#pragma unroll
            for (int bb = 0; bb < 2; ++bb)
                nsq_p[bb] = *(const floatx4*)&bsqn[cb1 + (bw * 2 + bb) * 16 + l4 * 4];
#pragma unroll
            for (int qt = 0; qt < 4; ++qt)
                tg_p[qt] = __hip_atomic_load(&thr_g[qglob[qt]], __ATOMIC_RELAXED,
                                             __HIP_MEMORY_SCOPE_AGENT);
        }

        // acc init = -0.5*bs (D-layout row = l4*4+r)
        floatx4 acc[2][4];
#pragma unroll
        for (int bb = 0; bb < 2; ++bb)
#pragma unroll
            for (int qt = 0; qt < 4; ++qt) acc[bb][qt] = ini[bb];
        // MFMA: 2 bank-tiles x 4 query-tiles, K = 128 (4 ksteps of 32)
#pragma unroll
        for (int ks = 0; ks < 4; ++ks) {
            bf16x8 af[2];
#pragma unroll
            for (int bb = 0; bb < 2; ++bb)
                af[bb] = *(const bf16x8*)
                    &sm.bt[cur][((bw * 2 + bb) * 4 + ks) * 512 + lane * 8];
#pragma unroll
            for (int bb = 0; bb < 2; ++bb)
#pragma unroll
                for (int qt = 0; qt < 4; ++qt)
                    acc[bb][qt] = mfma16(af[bb], qf[qt][ks], acc[bb][qt]);
        }

        // gates -> thresholds on raw acc (loosening guards transform rounding)
        float h[4];
#pragma unroll
        for (int qt = 0; qt < 4; ++qt) {
            g[qt] = fminf(g[qt], __int_as_float(tg[qt]));
            h[qt] = 0.5f * (qs4[qt] - g[qt] * 1.0000005f);
        }

        // selection: 1 reg-max + 1 v_cmp per 4 elements; rare insert path
#pragma unroll
        for (int bb = 0; bb < 2; ++bb) {
#pragma unroll
            for (int qt = 0; qt < 4; ++qt) {
                float a0 = acc[bb][qt][0], a1 = acc[bb][qt][1];
                float a2 = acc[bb][qt][2], a3 = acc[bb][qt][3];
                float mx = fmaxf(fmaxf(a0, a1), fmaxf(a2, a3));
                if (__ballot(mx >= h[qt])) {
#pragma unroll
                    for (int r = 0; r < 4; ++r) {
                        float a = acc[bb][qt][r];
                        if (a >= h[qt]) {
                            float d2 = fmaxf(fmaf(-2.f, a, qs4[qt]), 0.f);
                            if (d2 <= g[qt]) {
                                t9[qt][K_NEI - 1] = d2;
#pragma unroll
                                for (int s = K_NEI - 1; s > 0; --s)
                                    ce(t9[qt][s - 1], t9[qt][s]);
                                g[qt] = fminf(g[qt], t9[qt][K_NEI - 1]);
                            }
                        }
                    }
                }
            }
        }
        // gate-merge events (ch = 0,1,2,3,7,15,23 -> mask 0x80808F):
        // exact quad pool -> publish 9th; leader keeps, followers clear.
        if ((0x80808Fu >> ch) & 1) {
#pragma unroll
            for (int qt = 0; qt < 4; ++qt) {
                quad_merge(t9[qt]);
                float nth = t9[qt][K_NEI - 1];
                g[qt] = fminf(g[qt], nth);
                if (l4 == 0) {
                    if (nth < lastpub[qt]) {
                        atomicMin(&thr_g[qglob[qt]], __float_as_int(nth));
                        lastpub[qt] = nth;
                    }
                } else {
                    // follower: reset so lists stay element-disjoint
#pragma unroll
                    for (int j = 0; j < K_NEI; ++j) t9[qt][j] = FLT_MAX;
                }
            }
        }
    }

    // ---- epilogue: pool quad (disjoint), then cross-wave (bw) via LDS -----
#pragma unroll
    for (int qt = 0; qt < 4; ++qt) quad_merge(t9[qt]);
    __syncthreads();            // last chunk's ds_reads done; bt area reusable
    if (bw == 0 && l4 == 0) {
#pragma unroll
        for (int qt = 0; qt < 4; ++qt)
#pragma unroll
            for (int j = 0; j < K_NEI; ++j)
                sm.pool[qloc[qt]][j] = t9[qt][j];
    }
    __syncthreads();
    if (bw == 1 && l4 == 0) {
#pragma unroll
        for (int qt = 0; qt < 4; ++qt) {
            float o[K_NEI];
#pragma unroll
            for (int j = 0; j < K_NEI; ++j) o[j] = sm.pool[qloc[qt]][j];
            merge9(t9[qt], o);   // block-pooled sorted top-9 for this segment
            float* dst = part + ((size_t)(qbase + qloc[qt]) * SEGS + seg) * K_NEI;
#pragma unroll
            for (int j = 0; j < K_NEI; ++j) dst[j] = t9[qt][j];
        }
    }

    // ---- fused final: last seg-block of this qgroup folds 32 sorted lists --
    __threadfence();            // release our part writes device-wide
    __syncthreads();
    if (tid == 0)
        sm_last = (atomicAdd(&done[bq], 1) == SEGS - 1) ? 1 : 0;
    __syncthreads();
    if (sm_last && tid < QB) {
        int q = qbase + tid;
        const float* p = part + (size_t)q * SEGS * K_NEI;
        float R[K_NEI], nx[K_NEI];
#pragma unroll
        for (int j = 0; j < K_NEI; ++j)
            R[j] = __hip_atomic_load(p + j, __ATOMIC_RELAXED,
                                     __HIP_MEMORY_SCOPE_AGENT);
#pragma unroll
        for (int j = 0; j < K_NEI; ++j)
            nx[j] = __hip_atomic_load(p + K_NEI + j, __ATOMIC_RELAXED,
                                      __HIP_MEMORY_SCOPE_AGENT);
#pragma unroll 1
        for (int s = 1; s < SEGS; ++s) {
            float o[K_NEI];
#pragma unroll
            for (int j = 0; j < K_NEI; ++j) o[j] = nx[j];
            if (s + 1 < SEGS) {
#pragma unroll
                for (int j = 0; j < K_NEI; ++j)
                    nx[j] = __hip_atomic_load(p + (s + 1) * K_NEI + j,
                                              __ATOMIC_RELAXED,
                                              __HIP_MEMORY_SCOPE_AGENT);
            }
            merge9(R, o);
        }
        float sum = 0.f;
#pragma unroll
        for (int j = 0; j < K_NEI; ++j) sum += sqrtf(fmaxf(R[j], 0.f));
        out[q] = sum * (1.0f / 9.0f);
    }
}

// ---------------------------------------------------------------------------
extern "C" void kernel_launch(void* const* d_in, const int* in_sizes, int n_in,
                              void* d_out, int out_size, void* d_ws, size_t ws_size,
                              hipStream_t stream) {
    const float* feats = (const float*)d_in[0];   // [M, D]
    const float* bank  = (const float*)d_in[1];   // [N, D]

    char* w = (char*)d_ws;
    __hip_bfloat16* bankbf = (__hip_bfloat16*)w;                       // 16 MB
    __hip_bfloat16* featbf = (__hip_bfloat16*)(w + (size_t)N * D * 2); // 1 MB
    float* bsqn = (float*)(w + (size_t)(N + M) * D * 2);               // 256 KB
    float* qsqp = bsqn + N;                                            // 16 KB
    float* part = qsqp + M;                                            // 4.5 MB
    int*   thr_g = (int*)(part + (size_t)M * SEGS * K_NEI);            // 16 KB
    int*   done  = thr_g + M;                                          // 128 B
    float* out  = (float*)d_out;

    prep_kernel<<<(N + M) / 4, 256, 0, stream>>>(bank, feats, bankbf, featbf,
                                                 bsqn, qsqp, thr_g, done);
    knn_main<<<QGROUPS * SEGS, 256, 0, stream>>>(bankbf, featbf, bsqn, qsqp,
                                                 thr_g, part, done, out);
}

// Round 9
// 423.476 us; speedup vs baseline: 1.5468x; 1.2693x over previous
//
#include <hip/hip_runtime.h>
#include <hip/hip_bf16.h>
#include <float.h>

#define K_NEI 9
#define M 4096
#define N 65536
#define D 128
#define SEGS 32
#define SEG_LEN (N / SEGS)     // 2048 bank rows per segment
#define QB 128                 // queries per block
#define BB 64                  // bank rows per chunk
#define CHUNKS (SEG_LEN / BB)  // 32
#define QGROUPS (M / QB)       // 32

typedef __bf16 bf16x8 __attribute__((ext_vector_type(8)));
typedef float floatx4 __attribute__((ext_vector_type(4)));

static __device__ inline floatx4 mfma16(bf16x8 a, bf16x8 b, floatx4 c) {
    return __builtin_amdgcn_mfma_f32_16x16x32_bf16(a, b, c, 0, 0, 0);
}

// async global->LDS, 16B per lane, dest = lds_base + lane*16
#define GL_LDS16(gp, lp)                                                     \
    __builtin_amdgcn_global_load_lds(                                        \
        (const __attribute__((address_space(1))) unsigned int*)(const void*)(gp), \
        (__attribute__((address_space(3))) unsigned int*)(void*)(lp), 16, 0, 0)

// ---- sorted-9 toolkit -----------------------------------------------------
static __device__ inline void ce(float& a, float& b) {
    float lo = fminf(a, b), hi = fmaxf(a, b); a = lo; b = hi;
}
// canonical optimal 25-CE / depth-7 sorting network for 9 (ascending)
static __device__ inline void sort9(float t[K_NEI]) {
    ce(t[0],t[3]); ce(t[1],t[7]); ce(t[2],t[5]); ce(t[4],t[8]);
    ce(t[0],t[7]); ce(t[2],t[4]); ce(t[3],t[8]); ce(t[5],t[6]);
    ce(t[0],t[2]); ce(t[1],t[3]); ce(t[4],t[5]); ce(t[7],t[8]);
    ce(t[1],t[4]); ce(t[3],t[6]); ce(t[5],t[7]);
    ce(t[0],t[1]); ce(t[2],t[4]); ce(t[3],t[5]); ce(t[6],t[8]);
    ce(t[2],t[3]); ce(t[4],t[5]); ce(t[6],t[7]);
    ce(t[1],t[2]); ce(t[3],t[4]); ce(t[5],t[6]);
}
// t, o sorted ascending -> t = sorted 9 smallest of union (bitonic min trick)
static __device__ inline void merge9(float t[K_NEI], const float o[K_NEI]) {
    float m[K_NEI];
#pragma unroll
    for (int i = 0; i < K_NEI; ++i) m[i] = fminf(t[i], o[K_NEI - 1 - i]);
    sort9(m);
#pragma unroll
    for (int i = 0; i < K_NEI; ++i) t[i] = m[i];
}
// pool the 4 partner lanes (lane ^16, ^32): all 4 end with identical exact
// top-9 of the quad's union. ONLY valid if the 4 lists are element-disjoint.
static __device__ inline void quad_merge(float t[K_NEI]) {
    float o[K_NEI];
#pragma unroll
    for (int i = 0; i < K_NEI; ++i) o[i] = __shfl_xor(t[i], 16, 64);
    merge9(t, o);
#pragma unroll
    for (int i = 0; i < K_NEI; ++i) o[i] = __shfl_xor(t[i], 32, 64);
    merge9(t, o);
}

// ---------------------------------------------------------------------------
// Kernel 1 (fused prep): fp32 -> bf16 convert + row norms for BOTH inputs,
// plus per-call init of thr_g (gates) and done (qgroup counters) -- ws is
// re-poisoned 0xAA before every timed call.
// ---------------------------------------------------------------------------
__global__ void prep_kernel(const float* __restrict__ bank,
                            const float* __restrict__ feats,
                            __hip_bfloat16* __restrict__ bankbf,
                            __hip_bfloat16* __restrict__ featbf,
                            float* __restrict__ bsqn,
                            float* __restrict__ qsq,
                            int* __restrict__ thr_g,
                            int* __restrict__ done) {
    int row  = (int)((blockIdx.x * blockDim.x + threadIdx.x) >> 6);
    int lane = threadIdx.x & 63;
    if (row >= N + M) return;
    const float* src = (row < N) ? (bank + (size_t)row * D)
                                 : (feats + (size_t)(row - N) * D);
    __hip_bfloat16* dst = (row < N) ? (bankbf + (size_t)row * D)
                                    : (featbf + (size_t)(row - N) * D);
    float2 v = ((const float2*)src)[lane];
    float s = v.x * v.x + v.y * v.y;
    dst[lane * 2 + 0] = __float2bfloat16(v.x);
    dst[lane * 2 + 1] = __float2bfloat16(v.y);
#pragma unroll
    for (int off = 32; off > 0; off >>= 1) s += __shfl_down(s, off, 64);
    if (lane == 0) {
        if (row < N) {
            bsqn[row] = -0.5f * s;
        } else {
            qsq[row - N] = s;
            thr_g[row - N] = 0x7f7f7f7f;   // 3.39e38f
        }
    }
    if (lane == 1 && row >= N && row < N + QGROUPS) done[row - N] = 0;
}

// ---------------------------------------------------------------------------
// Kernel 2: MFMA distance GEMM + fused per-query top-9 + fused final merge.
// grid = 1024 blocks of 256 threads (4 waves); 32 KB LDS double buffer.
//
// ROUND-8/7 LESSON: occupancy is register-bound, and gfx950's unified
// VGPR/AGPR file counts the accumulators against the wave budget. Pushing
// __launch_bounds__ without cutting demand (qf 64 + t9 36 + acc 32 + misc
// ~40 = ~172 regs) just forced scratch spills (WRITE_SIZE 447 -> 134 MB).
// THIS ROUND cuts demand structurally: each wave owns 2 QUERY TILES
// (32 queries, exclusive) x all 4 BANK TILES (was 4x2): same 8 MFMA/ks,
// but qf 64->32 VGPR, t9 36->18, total ~147 < 170 budget at (256,3):
// zero spill, 3 blocks/CU = 12 waves/CU. Wave-exclusive queries also kill
// the cross-wave LDS pool (epilogue = quad_merge + direct store).
// XCD-swizzled: seg%8 == blockIdx%8 for bank-segment L2 locality.
//
// acc init = -0.5*bs (fp32) => acc = dot - 0.5*bs => d2 = qs - 2*acc.
// bsqn + thr_g for chunk ch+1 prefetched into registers alongside staging.
// Gate: d2 <= g  <=>  acc >= h = 0.5*(qs - g): 1 reg-max + 1 v_cmp per 4
// elements. Gate-merge events (ch = 0,1,2,3,7,15,23): each 4-lane quad
// computes its EXACT pooled top-9 (disjoint lists: leader keeps, followers
// clear -- round-5 bug) and publishes the pooled 9th (atomicMin, dirty-skip).
// Last seg-block per qgroup (done-counter + threadfence + agent-scope loads)
// folds the 32 sorted per-seg lists and writes the output.
// ---------------------------------------------------------------------------
__global__ __launch_bounds__(256, 3)
void knn_main(const __hip_bfloat16* __restrict__ bankbf,
              const __hip_bfloat16* __restrict__ featbf,
              const float* __restrict__ bsqn,
              const float* __restrict__ qsqp,
              int* __restrict__ thr_g,
              float* __restrict__ part,
              int* __restrict__ done,
              float* __restrict__ out) {
    __shared__ __align__(16) short sm_bt[2][16 * 512];  // 2 x 16 KB dbuf
    __shared__ int sm_last;

    const int tid  = threadIdx.x;
    const int lane = tid & 63;
    const int wv   = tid >> 6;
    // XCD swizzle: seg%8 == blockIdx%8
    const int s8  = blockIdx.x & 7;
    const int t_  = blockIdx.x >> 3;
    const int bq  = t_ & 31;
    const int seg = ((t_ >> 5) << 3) | s8;
    const int qbase  = bq * QB;
    const int cbase0 = seg * SEG_LEN;
    const int l15 = lane & 15, l4 = lane >> 4;

    // query fragments (B operand): wave wv owns queries wv*32 .. wv*32+31
    bf16x8 qf[2][4];
    float qs4[2];
    int qglob[2];
#pragma unroll
    for (int qt = 0; qt < 2; ++qt) {
        int q = qbase + wv * 32 + qt * 16 + l15;
        qglob[qt] = q;
        qs4[qt]   = qsqp[q];
#pragma unroll
        for (int ks = 0; ks < 4; ++ks)
            qf[qt][ks] = *(const bf16x8*)(featbf + (size_t)q * D + ks * 32 + l4 * 8);
    }

    float t9[2][K_NEI];
    float g[2], lastpub[2];
#pragma unroll
    for (int qt = 0; qt < 2; ++qt) {
        g[qt] = FLT_MAX;
        lastpub[qt] = FLT_MAX;
#pragma unroll
        for (int j = 0; j < K_NEI; ++j) t9[qt][j] = FLT_MAX;
    }

    // prologue: stage chunk 0 into buffer 0 (16 regions; wave wv -> bt=wv)
#pragma unroll
    for (int ks = 0; ks < 4; ++ks) {
        const __hip_bfloat16* gp =
            bankbf + (size_t)(cbase0 + wv * 16 + l15) * D + ks * 32 + l4 * 8;
        GL_LDS16(gp, &sm_bt[0][(wv * 4 + ks) * 512]);
    }
    // prologue register prefetch for chunk 0
    floatx4 nsq_p[4];
    int tg_p[2];
#pragma unroll
    for (int bb = 0; bb < 4; ++bb)
        nsq_p[bb] = *(const floatx4*)&bsqn[cbase0 + bb * 16 + l4 * 4];
#pragma unroll
    for (int qt = 0; qt < 2; ++qt)
        tg_p[qt] = __hip_atomic_load(&thr_g[qglob[qt]], __ATOMIC_RELAXED,
                                     __HIP_MEMORY_SCOPE_AGENT);

#pragma unroll 1
    for (int ch = 0; ch < CHUNKS; ++ch) {
        const int cur = ch & 1;
        __syncthreads();  // drains own vmcnt -> buf[cur] + prefetch regs ready

        // consume this chunk's prefetched values (already landed)
        floatx4 ini[4];
        int tg[2];
#pragma unroll
        for (int bb = 0; bb < 4; ++bb) ini[bb] = nsq_p[bb];
#pragma unroll
        for (int qt = 0; qt < 2; ++qt) tg[qt] = tg_p[qt];

        // issue next chunk's staging + register prefetches immediately
        if (ch + 1 < CHUNKS) {
            const int cb1 = cbase0 + (ch + 1) * BB;
#pragma unroll
            for (int ks = 0; ks < 4; ++ks) {
                const __hip_bfloat16* gp =
                    bankbf + (size_t)(cb1 + wv * 16 + l15) * D + ks * 32 + l4 * 8;
                GL_LDS16(gp, &sm_bt[cur ^ 1][(wv * 4 + ks) * 512]);
            }
#pragma unroll
            for (int bb = 0; bb < 4; ++bb)
                nsq_p[bb] = *(const floatx4*)&bsqn[cb1 + bb * 16 + l4 * 4];
#pragma unroll
            for (int qt = 0; qt < 2; ++qt)
                tg_p[qt] = __hip_atomic_load(&thr_g[qglob[qt]], __ATOMIC_RELAXED,
                                             __HIP_MEMORY_SCOPE_AGENT);
        }

        // acc init = -0.5*bs (D-layout row = l4*4+r)
        floatx4 acc[4][2];
#pragma unroll
        for (int bb = 0; bb < 4; ++bb)
#pragma unroll
            for (int qt = 0; qt < 2; ++qt) acc[bb][qt] = ini[bb];
        // MFMA: 4 bank-tiles x 2 query-tiles, K = 128 (4 ksteps of 32)
#pragma unroll
        for (int ks = 0; ks < 4; ++ks) {
            bf16x8 af[4];
#pragma unroll
            for (int bb = 0; bb < 4; ++bb)
                af[bb] = *(const bf16x8*)
                    &sm_bt[cur][(bb * 4 + ks) * 512 + lane * 8];
#pragma unroll
            for (int bb = 0; bb < 4; ++bb)
#pragma unroll
                for (int qt = 0; qt < 2; ++qt)
                    acc[bb][qt] = mfma16(af[bb], qf[qt][ks], acc[bb][qt]);
        }

        // gates -> thresholds on raw acc (loosening guards transform rounding)
        float h[2];
#pragma unroll
        for (int qt = 0; qt < 2; ++qt) {
            g[qt] = fminf(g[qt], __int_as_float(tg[qt]));
            h[qt] = 0.5f * (qs4[qt] - g[qt] * 1.0000005f);
        }

        // selection: 1 reg-max + 1 v_cmp per 4 elements; rare insert path
#pragma unroll
        for (int bb = 0; bb < 4; ++bb) {
#pragma unroll
            for (int qt = 0; qt < 2; ++qt) {
                float a0 = acc[bb][qt][0], a1 = acc[bb][qt][1];
                float a2 = acc[bb][qt][2], a3 = acc[bb][qt][3];
                float mx = fmaxf(fmaxf(a0, a1), fmaxf(a2, a3));
                if (__ballot(mx >= h[qt])) {
#pragma unroll
                    for (int r = 0; r < 4; ++r) {
                        float a = acc[bb][qt][r];
                        if (a >= h[qt]) {
                            float d2 = fmaxf(fmaf(-2.f, a, qs4[qt]), 0.f);
                            if (d2 <= g[qt]) {
                                t9[qt][K_NEI - 1] = d2;
#pragma unroll
                                for (int s = K_NEI - 1; s > 0; --s)
                                    ce(t9[qt][s - 1], t9[qt][s]);
                                g[qt] = fminf(g[qt], t9[qt][K_NEI - 1]);
                            }
                        }
                    }
                }
            }
        }
        // gate-merge events (ch = 0,1,2,3,7,15,23 -> mask 0x80808F):
        // exact quad pool -> publish 9th; leader keeps, followers clear.
        if ((0x80808Fu >> ch) & 1) {
#pragma unroll
            for (int qt = 0; qt < 2; ++qt) {
                quad_merge(t9[qt]);
                float nth = t9[qt][K_NEI - 1];
                g[qt] = fminf(g[qt], nth);
                if (l4 == 0) {
                    if (nth < lastpub[qt]) {
                        atomicMin(&thr_g[qglob[qt]], __float_as_int(nth));
                        lastpub[qt] = nth;
                    }
                } else {
                    // follower: reset so lists stay element-disjoint
#pragma unroll
                    for (int j = 0; j < K_NEI; ++j) t9[qt][j] = FLT_MAX;
                }
            }
        }
    }

    // ---- epilogue: quad pool (disjoint) = exact block top-9 per query -----
#pragma unroll
    for (int qt = 0; qt < 2; ++qt) quad_merge(t9[qt]);
    if (l4 == 0) {
#pragma unroll
        for (int qt = 0; qt < 2; ++qt) {
            float* dst = part + ((size_t)qglob[qt] * SEGS + seg) * K_NEI;
#pragma unroll
            for (int j = 0; j < K_NEI; ++j) dst[j] = t9[qt][j];
        }
    }

    // ---- fused final: last seg-block of this qgroup folds 32 sorted lists --
    __threadfence();            // release our part writes device-wide
    __syncthreads();
    if (tid == 0)
        sm_last = (atomicAdd(&done[bq], 1) == SEGS - 1) ? 1 : 0;
    __syncthreads();
    if (sm_last && tid < QB) {
        int q = qbase + tid;
        const float* p = part + (size_t)q * SEGS * K_NEI;
        float R[K_NEI], nx[K_NEI];
#pragma unroll
        for (int j = 0; j < K_NEI; ++j)
            R[j] = __hip_atomic_load(p + j, __ATOMIC_RELAXED,
                                     __HIP_MEMORY_SCOPE_AGENT);
#pragma unroll
        for (int j = 0; j < K_NEI; ++j)
            nx[j] = __hip_atomic_load(p + K_NEI + j, __ATOMIC_RELAXED,
                                      __HIP_MEMORY_SCOPE_AGENT);
#pragma unroll 1
        for (int s = 1; s < SEGS; ++s) {
            float o[K_NEI];
#pragma unroll
            for (int j = 0; j < K_NEI; ++j) o[j] = nx[j];
            if (s + 1 < SEGS) {
#pragma unroll
                for (int j = 0; j < K_NEI; ++j)
                    nx[j] = __hip_atomic_load(p + (s + 1) * K_NEI + j,
                                              __ATOMIC_RELAXED,
                                              __HIP_MEMORY_SCOPE_AGENT);
            }
            merge9(R, o);
        }
        float sum = 0.f;
#pragma unroll
        for (int j = 0; j < K_NEI; ++j) sum += sqrtf(fmaxf(R[j], 0.f));
        out[q] = sum * (1.0f / 9.0f);
    }
}

// ---------------------------------------------------------------------------
extern "C" void kernel_launch(void* const* d_in, const int* in_sizes, int n_in,
                              void* d_out, int out_size, void* d_ws, size_t ws_size,
                              hipStream_t stream) {
    const float* feats = (const float*)d_in[0];   // [M, D]
    const float* bank  = (const float*)d_in[1];   // [N, D]

    char* w = (char*)d_ws;
    __hip_bfloat16* bankbf = (__hip_bfloat16*)w;                       // 16 MB
    __hip_bfloat16* featbf = (__hip_bfloat16*)(w + (size_t)N * D * 2); // 1 MB
    float* bsqn = (float*)(w + (size_t)(N + M) * D * 2);               // 256 KB
    float* qsqp = bsqn + N;                                            // 16 KB
    float* part = qsqp + M;                                            // 4.5 MB
    int*   thr_g = (int*)(part + (size_t)M * SEGS * K_NEI);            // 16 KB
    int*   done  = thr_g + M;                                          // 128 B
    float* out  = (float*)d_out;

    prep_kernel<<<(N + M) / 4, 256, 0, stream>>>(bank, feats, bankbf, featbf,
                                                 bsqn, qsqp, thr_g, done);
    knn_main<<<QGROUPS * SEGS, 256, 0, stream>>>(bankbf, featbf, bsqn, qsqp,
                                                 thr_g, part, done, out);
}